// Round 5
// baseline (79.009 us; speedup 1.0000x reference)
//
#include <hip/hip_runtime.h>
#include <math.h>

// Problem constants (setup_inputs is fixed: B=64, T=512, H=768, L=400)
namespace {
constexpr int kB  = 64;
constexpr int kT  = 512;
constexpr int kH  = 768;
constexpr int kHm = 767;        // H-1 feature channels
constexpr int kL  = 400;        // max_label_length
constexpr int kC  = 16;         // k-chunks (parallel scan segments)
constexpr int kTC = kL / kC;    // 25 k-steps per chunk
constexpr int kBK = 16;         // register load-batch depth
constexpr int kLwPad = kL + kBK; // lw[k0+i] unconditional reads: max 414 < 416
}

__device__ __forceinline__ float sigmoidf_(float x) {
  return 1.0f / (1.0f + expf(-x));
}

// One block per batch element b (512 threads):
//  - sigmoid of alpha channel for all T steps (parallel) + block-reduce sum
//  - lane 0 runs the 400-step scalar recurrence, emitting (w, m, sel) per k
//    (out_k = s + w*x ; s_new = sel*s + m*x) and, per chunk boundary 25c,
//    the replay start r0 = last fire strictly before 25c (or 0).
__global__ __launch_bounds__(512) void k_rec(
    const float* __restrict__ hs, const int* __restrict__ labels,
    float* __restrict__ asum_ws, int* __restrict__ starts_ws,
    float4* __restrict__ wms) {
  __shared__ float a_lds[kT];
  __shared__ float red[kT];
  const int b = blockIdx.x;
  const int tid = threadIdx.x;

  float sig = sigmoidf_(hs[(size_t)b * kT * kH + (size_t)tid * kH + kHm]);
  a_lds[tid] = sig;
  red[tid] = sig;
  __syncthreads();
  for (int off = 256; off > 0; off >>= 1) {
    if (tid < off) red[tid] += red[tid + off];
    __syncthreads();
  }

  if (tid == 0) {
    const float as = red[0];
    asum_ws[b] = as;
    const int lab = labels[b];
    const float len = (float)(lab < kL ? lab : kL);
    const float scale = len / as;
    float a_r = 0.0f;
    int last_fire = -1;
    float4* wb = wms + b * kL;
    int* sb = starts_ws + b * kC;
    for (int c = 0; c < kC; ++c) {
      sb[c] = last_fire < 0 ? 0 : last_fire;  // replay from the fire itself
      const int kbase = c * kTC;
#pragma unroll
      for (int kk = 0; kk < kTC; ++kk) {
        const int k = kbase + kk;
        const float ak = a_lds[k] * scale;
        const float a_a = ak + a_r;
        const bool fired = (a_a >= 1.0f);
        const float w   = fired ? (1.0f - a_r) : ak;
        const float arn = fired ? (ak - (1.0f - a_r)) : a_a;  // exact ref expr
        const float m   = fired ? arn : ak;
        const float sel = fired ? 0.0f : 1.0f;
        wb[k] = make_float4(w, m, sel, 0.0f);
        if (fired) last_fire = k;
        a_r = arn;
      }
    }
  }
}

// Chunk-parallel scan, register-batched loads. Grid (3, B, kC), 256 threads.
// Block (x,b,c) produces out[b, 25c..25c+24, h-tile]; entry state is replayed
// from the last fire before 25c with the same fmaf chain (sel=0 at a fire
// resets the state -> bitwise-identical to the monolithic scan).
// The single multi-operand asm after each load batch forces all kBK loads to
// be issued back-to-back and live in VGPRs (defeats compiler load-sinking,
// which capped R2/R3 at ~2 outstanding loads/thread).
__global__ __launch_bounds__(256, 4) void k_scan(
    const float* __restrict__ hs, const int* __restrict__ labels,
    const float* __restrict__ asum_ws, const int* __restrict__ starts_ws,
    const float4* __restrict__ wms, float* __restrict__ out) {
  __shared__ float4 lw[kLwPad];
  const int b   = blockIdx.y;
  const int c   = blockIdx.z;
  const int tid = threadIdx.x;

  for (int i = tid; i < kLwPad; i += 256)
    lw[i] = (i < kL) ? wms[b * kL + i] : make_float4(0, 0, 0, 0);

  // n_hat = sum_b (len_b - alpha_sum_b)^2, once, in block (0,0,0)
  if (blockIdx.x == 0 && b == 0 && c == 0 && tid < kB) {
    const float as = asum_ws[tid];
    const int lab = labels[tid];
    const float len = (float)(lab < kL ? lab : kL);
    const float d = len - as;
    float v = d * d;
    for (int off = 32; off > 0; off >>= 1) v += __shfl_down(v, off, 64);
    if (tid == 0) out[(size_t)kB * kL * kHm] = v;
  }
  __syncthreads();

  const int kb = c * kTC;        // first stored k
  const int ke = kb + kTC;       // one past last stored k
  const int r0 = __builtin_amdgcn_readfirstlane(starts_ws[b * kC + c]);

  const int h = blockIdx.x * 256 + tid;
  const bool hok = (h < kHm);
  const float* __restrict__ px = hs + (size_t)b * kT * kH + h;
  float* __restrict__ po = out + (size_t)b * kL * kHm + h;

  float s = 0.0f;
  for (int k0 = r0; k0 < ke; k0 += kBK) {
    float x[kBK];
#pragma unroll
    for (int i = 0; i < kBK; ++i) {
      x[i] = px[(size_t)(k0 + i) * kH];  // max k0+i = 414 < T=512: in-bounds
    }
    // Force all kBK loads issued + resident before any use.
    asm volatile("" : "+v"(x[0]), "+v"(x[1]), "+v"(x[2]), "+v"(x[3]),
                      "+v"(x[4]), "+v"(x[5]), "+v"(x[6]), "+v"(x[7]),
                      "+v"(x[8]), "+v"(x[9]), "+v"(x[10]), "+v"(x[11]),
                      "+v"(x[12]), "+v"(x[13]), "+v"(x[14]), "+v"(x[15]));
#pragma unroll
    for (int i = 0; i < kBK; ++i) {
      const int k = k0 + i;
      if (k < ke) {                    // scalar-uniform guard
        const float4 c4 = lw[k];
        if (k >= kb) {                 // store phase (uniform)
          const float o = fmaf(c4.x, x[i], s);
          if (hok) po[(size_t)k * kHm] = o;
        }
        s = fmaf(c4.y, x[i], c4.z * s);  // replay & main share this chain
      }
    }
  }
}

extern "C" void kernel_launch(void* const* d_in, const int* in_sizes, int n_in,
                              void* d_out, int out_size, void* d_ws, size_t ws_size,
                              hipStream_t stream) {
  const float* hs     = (const float*)d_in[0];
  const int*   labels = (const int*)d_in[1];
  float* out = (float*)d_out;

  // ws layout: [0,256) alpha_sum (64 f32); [256, 4352) starts (64 x 16 i32);
  // [8192, 8192+410KB) (w,m,sel,_) float4 per (b,k).
  float*  asum_ws   = (float*)d_ws;
  int*    starts_ws = (int*)((char*)d_ws + 256);
  float4* wms       = (float4*)((char*)d_ws + 8192);

  k_rec<<<kB, 512, 0, stream>>>(hs, labels, asum_ws, starts_ws, wms);
  k_scan<<<dim3((kHm + 255) / 256, kB, kC), 256, 0, stream>>>(
      hs, labels, asum_ws, starts_ws, wms, out);
}

// Round 6
// 56.841 us; speedup vs baseline: 1.3900x; 1.3900x over previous
//
#include <hip/hip_runtime.h>
#include <math.h>

// Problem constants (setup_inputs is fixed: B=64, T=512, H=768, L=400)
namespace {
constexpr int kB  = 64;
constexpr int kT  = 512;
constexpr int kH  = 768;
constexpr int kH4 = kH / 4;     // 192 float4 per row
constexpr int kHm = 767;        // H-1 feature channels
constexpr int kL  = 400;        // max_label_length
constexpr int kC  = 8;          // k-chunks
constexpr int kTC = kL / kC;    // 50 steps per chunk
constexpr int kTh = 192;        // threads: each owns 4 consecutive h
}

__device__ __forceinline__ float sigmoidf_(float x) {
  return 1.0f / (1.0f + expf(-x));
}

// One block per batch b: sigmoid+reduce alpha_sum; lane 0 walks the 400-step
// scalar recurrence emitting per-k coeffs (w,m,sel) with
//   out_k = s + w*x ;  s_new = sel*s + m*x   (sel=0 at a fire resets state)
// plus per chunk c: rstart[b][c] = chain start for the chunk-suffix vector Q_c
// (last fire inside chunk, else chunk begin) and cstart[b][c] = last fired
// chunk strictly before c (else 0), so entry(c) = sum_{j=cstart..c-1} Q_j.
__global__ __launch_bounds__(512) void k_rec(
    const float* __restrict__ hs, const int* __restrict__ labels,
    float* __restrict__ asum_ws, int* __restrict__ rstart_ws,
    int* __restrict__ cstart_ws, float4* __restrict__ wms) {
  __shared__ float a_lds[kT];
  __shared__ float red[kT];
  const int b = blockIdx.x;
  const int tid = threadIdx.x;

  float sig = sigmoidf_(hs[(size_t)b * kT * kH + (size_t)tid * kH + kHm]);
  a_lds[tid] = sig;
  red[tid] = sig;
  __syncthreads();
  for (int off = 256; off > 0; off >>= 1) {
    if (tid < off) red[tid] += red[tid + off];
    __syncthreads();
  }

  if (tid == 0) {
    const float as = red[0];
    asum_ws[b] = as;
    const int lab = labels[b];
    const float len = (float)(lab < kL ? lab : kL);
    const float scale = len / as;
    float a_r = 0.0f;
    int lfc = -1;   // last fired chunk so far
    float4* wb = wms + b * kL;
    for (int c = 0; c < kC; ++c) {
      cstart_ws[b * kC + c] = lfc < 0 ? 0 : lfc;
      int lf = -1;  // last fire inside this chunk
      const int kbase = c * kTC;
#pragma unroll
      for (int kk = 0; kk < kTC; ++kk) {
        const int k = kbase + kk;
        const float ak = a_lds[k] * scale;
        const float a_a = ak + a_r;
        const bool fired = (a_a >= 1.0f);
        const float w   = fired ? (1.0f - a_r) : ak;
        const float arn = fired ? (ak - (1.0f - a_r)) : a_a;  // exact ref expr
        const float m   = fired ? arn : ak;
        const float sel = fired ? 0.0f : 1.0f;
        wb[k] = make_float4(w, m, sel, 0.0f);
        if (fired) lf = k;
        a_r = arn;
      }
      rstart_ws[b * kC + c] = lf >= 0 ? lf : kbase;
      if (lf >= 0) lfc = c;
    }
  }
}

// Pass 1: per (b,c) compute the chunk-suffix state Q_c (768-wide, float4/thr):
// s=0; for k in [rstart, chunk_end): s = sel*s + m*x. If the chunk fired,
// rstart is the last fire (sel=0 there -> s=m*x, bitwise same as the
// monolithic chain). Work bounded by 50 steps -> no stragglers.
__global__ __launch_bounds__(kTh) void k_q(
    const float* __restrict__ hs, const int* __restrict__ labels,
    const float* __restrict__ asum_ws, const int* __restrict__ rstart_ws,
    const float4* __restrict__ wms, float4* __restrict__ q_ws,
    float* __restrict__ out) {
  __shared__ float4 lw[kL];
  const int b = blockIdx.x, c = blockIdx.y, tid = threadIdx.x;

  for (int i = tid; i < kL; i += kTh) lw[i] = wms[b * kL + i];

  // n_hat = sum_b (len_b - alpha_sum_b)^2, once, in block (0,0)
  if (b == 0 && c == 0 && tid < kB) {
    const float as = asum_ws[tid];
    const int lab = labels[tid];
    const float len = (float)(lab < kL ? lab : kL);
    const float d = len - as;
    float v = d * d;
    for (int off = 32; off > 0; off >>= 1) v += __shfl_down(v, off, 64);
    if (tid == 0) out[(size_t)kB * kL * kHm] = v;
  }
  __syncthreads();

  const int r1 = __builtin_amdgcn_readfirstlane(rstart_ws[b * kC + c]);
  const int ce = c * kTC + kTC;
  const float4* __restrict__ px = (const float4*)(hs + (size_t)b * kT * kH) + tid;

  float4 s = make_float4(0.f, 0.f, 0.f, 0.f);
#pragma unroll 5
  for (int k = r1; k < ce; ++k) {
    const float4 x = px[(size_t)k * kH4];
    const float4 cf = lw[k];
    s.x = fmaf(cf.y, x.x, cf.z * s.x);
    s.y = fmaf(cf.y, x.y, cf.z * s.y);
    s.z = fmaf(cf.y, x.z, cf.z * s.z);
    s.w = fmaf(cf.y, x.w, cf.z * s.w);
  }
  q_ws[(size_t)(b * kC + c) * kH4 + tid] = s;
}

// Pass 2: per (b,c) compose entry state (<=7 independent L2-hot float4 loads,
// summed for j in [cstart, c)), then scan exactly 50 steps with float4 loads
// (16 B/lane) and streaming dword stores.
__global__ __launch_bounds__(kTh) void k_scan(
    const float* __restrict__ hs, const int* __restrict__ cstart_ws,
    const float4* __restrict__ wms, const float4* __restrict__ q_ws,
    float* __restrict__ out) {
  __shared__ float4 lw[kL];
  const int b = blockIdx.x, c = blockIdx.y, tid = threadIdx.x;

  for (int i = tid; i < kL; i += kTh) lw[i] = wms[b * kL + i];
  __syncthreads();

  const int cs = __builtin_amdgcn_readfirstlane(cstart_ws[b * kC + c]);

  // Entry state: sum of chunk-suffix vectors Q_j, j in [cs, c). Load all 7
  // candidates unconditionally (independent, overlapped), add the needed ones.
  float4 s = make_float4(0.f, 0.f, 0.f, 0.f);
  {
    const float4* qb = q_ws + (size_t)b * kC * kH4 + tid;
    float4 qv[kC - 1];
#pragma unroll
    for (int j = 0; j < kC - 1; ++j) qv[j] = qb[(size_t)j * kH4];
#pragma unroll
    for (int j = 0; j < kC - 1; ++j) {
      if (j >= cs && j < c) {
        s.x += qv[j].x; s.y += qv[j].y; s.z += qv[j].z; s.w += qv[j].w;
      }
    }
  }

  const int cb = c * kTC, ce = cb + kTC;
  const float4* __restrict__ px = (const float4*)(hs + (size_t)b * kT * kH) + tid;
  const int h0 = 4 * tid;
  float* __restrict__ po = out + (size_t)b * kL * kHm + h0;
  const bool w3 = (h0 + 3 < kHm);  // only thread 191's 4th lane is cut

#pragma unroll 10
  for (int k = cb; k < ce; ++k) {
    const float4 x = px[(size_t)k * kH4];
    const float4 cf = lw[k];
    const float o0 = fmaf(cf.x, x.x, s.x);
    const float o1 = fmaf(cf.x, x.y, s.y);
    const float o2 = fmaf(cf.x, x.z, s.z);
    const float o3 = fmaf(cf.x, x.w, s.w);
    float* r = po + (size_t)k * kHm;
    r[0] = o0; r[1] = o1; r[2] = o2;
    if (w3) r[3] = o3;
    s.x = fmaf(cf.y, x.x, cf.z * s.x);
    s.y = fmaf(cf.y, x.y, cf.z * s.y);
    s.z = fmaf(cf.y, x.z, cf.z * s.z);
    s.w = fmaf(cf.y, x.w, cf.z * s.w);
  }
}

extern "C" void kernel_launch(void* const* d_in, const int* in_sizes, int n_in,
                              void* d_out, int out_size, void* d_ws, size_t ws_size,
                              hipStream_t stream) {
  const float* hs     = (const float*)d_in[0];
  const int*   labels = (const int*)d_in[1];
  float* out = (float*)d_out;

  // ws layout: [0,256) alpha_sum (64 f32); [256,2304) rstart (64x8 i32);
  // [2304,4352) cstart; [8192, +410KB) coeff float4 per (b,k);
  // [512KB, +1.57MB) Q vectors (64*8 rows x 768 f32).
  float*  asum_ws   = (float*)d_ws;
  int*    rstart_ws = (int*)((char*)d_ws + 256);
  int*    cstart_ws = (int*)((char*)d_ws + 2304);
  float4* wms       = (float4*)((char*)d_ws + 8192);
  float4* q_ws      = (float4*)((char*)d_ws + (512 << 10));

  k_rec<<<kB, 512, 0, stream>>>(hs, labels, asum_ws, rstart_ws, cstart_ws, wms);
  k_q<<<dim3(kB, kC), kTh, 0, stream>>>(hs, labels, asum_ws, rstart_ws, wms,
                                        q_ws, out);
  k_scan<<<dim3(kB, kC), kTh, 0, stream>>>(hs, cstart_ws, wms, q_ws, out);
}